// Round 4
// baseline (649.333 us; speedup 1.0000x reference)
//
#include <hip/hip_runtime.h>
#include <hip/hip_bf16.h>

typedef unsigned short u16;
typedef unsigned int   u32;

#define N_   32
#define T_   32
#define V_   128
#define CIN_ 264
#define CO_  64
#define KT_  9
#define EPS_ 1e-3f

// ---- param table (float offsets inside ws) ----
#define OFF_DBN_S 0          // 33792
#define OFF_DBN_O 33792      // 33792
#define OFF_W0    67584      // 264*64 (f32 copy, unused by mfma path; harmless)
#define OFF_BW0   84480      // 64
#define OFF_A0S   84544
#define OFF_A0O   84608
#define OFF_B0S   84672      // includes bt0 fold
#define OFF_B0O   84736
#define OFF_W1    84800      // 64*64 f32 (pw1)
#define OFF_BW1   88896
#define OFF_A1S   88960
#define OFF_A1O   89024
#define OFF_B1S   89088      // includes bt1 fold
#define OFF_B1O   89152
#define PREP_TOTAL 110464    // + W0A (64*288) + WTA (9*64*64)

// ---- ws byte layout (footprint unchanged from round-3 proven layout) ----
#define B_P    0
#define B_FLAG 360448
#define B_W0A  360512                    // bf16 64 x 288  (36864 B)
#define B_WTA  397440                    // bf16 9 x 64 x 64 (73728 B)
#define B_H0   524288                    // (unused this round)
#define B_G0   (B_H0 + 16777216)         // bf16 [n][t][w][i]  16 MB
#define B_L0   (B_G0 + 16777216)         // f32  [n][c][t][v]  64 MB
#define B_G1P  (B_L0 + 33554432)         // f32  [n][c][t]
#define B_END  (B_G1P + 262144)

typedef short bf16x8 __attribute__((ext_vector_type(8)));
typedef float f32x4  __attribute__((ext_vector_type(4)));

__device__ __forceinline__ float bf2f(u16 u) { return __uint_as_float(((u32)u) << 16); }
__device__ __forceinline__ u16 f2bf(float f) {
    u32 x = __float_as_uint(f);
    return (u16)((x + 0x7fffu + ((x >> 16) & 1u)) >> 16);
}
__device__ __forceinline__ float ldin(const void* p, u32 i, int f32) {
    return f32 ? ((const float*)p)[i] : bf2f(((const u16*)p)[i]);
}

// ---------------- dtype detect (bf16 vs f32 input buffers) ----------------
__global__ void k_detect(const void* a, int* flag) {
    if (threadIdx.x == 0 && blockIdx.x == 0) {
        const u16* p = (const u16*)a;
        int cnt = 0;
        for (int i = 0; i < 64; ++i) {
            float v = bf2f(p[2 * i]);
            if (v >= 0.f && v <= 1.0f) ++cnt;
        }
        *flag = (cnt >= 56) ? 0 : 1;
    }
}

// ---------------- param prep: BN folds + bf16 MFMA weight layouts ----------------
__global__ void k_prep(const void* dbn_g, const void* dbn_b, const void* dbn_m, const void* dbn_v,
                       const void* w0, const void* bw0,
                       const void* g0a, const void* b0a, const void* m0a, const void* v0a,
                       const void* bt0, const void* g0b, const void* b0b, const void* m0b, const void* v0b,
                       const void* w1, const void* bw1,
                       const void* g1a, const void* b1a, const void* m1a, const void* v1a,
                       const void* bt1, const void* g1b, const void* b1b, const void* m1b, const void* v1b,
                       const void* wt0,
                       float* P, u16* W0A, u16* WTA, const int* flagp)
{
    const int f32 = *flagp;
    int i = blockIdx.x * 256 + threadIdx.x;
    if (i < 33792) {
        float s = ldin(dbn_g, i, f32) * rsqrtf(ldin(dbn_v, i, f32) + EPS_);
        P[OFF_DBN_S + i] = s;
        P[OFF_DBN_O + i] = ldin(dbn_b, i, f32) - ldin(dbn_m, i, f32) * s;
    } else if (i < 50688) { int j = i - 33792; P[OFF_W0 + j] = ldin(w0, j, f32); }
    else if (i < 50752) { int j = i - 50688; P[OFF_BW0 + j] = ldin(bw0, j, f32); }
    else if (i < 50816) { int j = i - 50752;
        float s = ldin(g0a, j, f32) * rsqrtf(ldin(v0a, j, f32) + EPS_);
        P[OFF_A0S + j] = s; P[OFF_A0O + j] = ldin(b0a, j, f32) - ldin(m0a, j, f32) * s;
    } else if (i < 50880) { int j = i - 50816;
        float s = ldin(g0b, j, f32) * rsqrtf(ldin(v0b, j, f32) + EPS_);
        P[OFF_B0S + j] = s; P[OFF_B0O + j] = (ldin(bt0, j, f32) - ldin(m0b, j, f32)) * s + ldin(b0b, j, f32);
    } else if (i < 54976) { int j = i - 50880; P[OFF_W1 + j] = ldin(w1, j, f32); }
    else if (i < 55040) { int j = i - 54976; P[OFF_BW1 + j] = ldin(bw1, j, f32); }
    else if (i < 55104) { int j = i - 55040;
        float s = ldin(g1a, j, f32) * rsqrtf(ldin(v1a, j, f32) + EPS_);
        P[OFF_A1S + j] = s; P[OFF_A1O + j] = ldin(b1a, j, f32) - ldin(m1a, j, f32) * s;
    } else if (i < 55168) { int j = i - 55104;
        float s = ldin(g1b, j, f32) * rsqrtf(ldin(v1b, j, f32) + EPS_);
        P[OFF_B1S + j] = s; P[OFF_B1O + j] = (ldin(bt1, j, f32) - ldin(m1b, j, f32)) * s + ldin(b1b, j, f32);
    } else if (i < 73600) {      // W0A[c][288]: w0^T, row 264 = bw0 (bias trick), 265.. = 0
        int j = i - 55168; int c = j / 288, ci = j - c * 288;
        float val = (ci < 264) ? ldin(w0, (u32)ci * 64 + c, f32)
                  : ((ci == 264) ? ldin(bw0, c, f32) : 0.f);
        W0A[j] = f2bf(val);
    } else if (i < 110464) {     // WTA[k][o][i] = wt0[k][0][i][o]
        int j = i - 73600; int k = j >> 12, rem = j & 4095, o = rem >> 6, ii = rem & 63;
        WTA[j] = f2bf(ldin(wt0, ((u32)(k * 64 + ii)) * 64 + o, f32));
    }
}

// ---------------- fused layer-0: gather+BN -> MFMA pw0 -> H(LDS) -> MFMA graph0+BN+PReLU -> g0 ----
// per (t, n), 256 threads. Run-based gather: for wave-uniform c2, 64 lanes read 64
// consecutive flat indices == consecutive source addresses (identity reshape insight).
#define XT_STRIDE 296
#define H_OFF     37888       // bytes; XT region = 64*296*2 = 37888 B; amT (34816 B) reuses it
__global__ __launch_bounds__(256) void k_l0(const void* __restrict__ xin, const void* __restrict__ bin,
                                            const void* __restrict__ cin2, const void* __restrict__ a,
                                            const void* __restrict__ imp0, const void* __restrict__ al0,
                                            const float* __restrict__ P, const u16* __restrict__ W0Ag,
                                            u16* __restrict__ g0, const int* __restrict__ flagp)
{
    __shared__ __align__(16) char SM[55296];
    u16* XT  = (u16*)SM;               // [64][296]
    u16* amT = (u16*)SM;               // [128][136] (phase B, after XT retired)
    u16* H   = (u16*)(SM + H_OFF);     // [64 c][136 v]

    const int f32 = *flagp;
    const int t = blockIdx.x, n = blockIdx.y;
    const int tid = threadIdx.x;
    const int lane = tid & 63, wid = tid >> 6;
    const int l16 = lane & 15, quad = lane >> 4;
    const int m0 = wid * 16;

    // ---- phase A: pointwise conv, two v-halves ----
    for (int vh = 0; vh < 2; ++vh) {
        if (vh) __syncthreads();                 // XT readers of previous half done
        // stage XT[lane][c2] for v in [vh*64, vh*64+64)
        for (int c2 = wid; c2 < 288; c2 += 4) {  // c2 wave-uniform
            if (c2 < 264) {
                u32 f0 = (u32)c2 * 4096u + (u32)t * 128u + (u32)(vh * 64);
                u32 vs0 = f0 / 8448u;
                u32 r0  = f0 - vs0 * 8448u;
                u32 ts0 = r0 / 264u;
                u32 cc0 = r0 - ts0 * 264u;
                u32 cc = cc0 + (u32)lane;
                u32 ts = ts0, vs = vs0;
                if (cc >= 264u) { cc -= 264u; ++ts; }
                if (ts >= 32u)  { ts -= 32u;  ++vs; }
                u32 base = ((u32)n * 32u + ts) * 128u + vs;
                float val;
                if (cc < 256u)      val = ldin(xin, base * 256u + cc, f32);
                else if (cc < 260u) val = ldin(bin, base * 4u + (cc - 256u), f32);
                else                val = ldin(cin2, base * 4u + (cc - 260u), f32);
                u32 ch = vs * 264u + cc;
                XT[lane * XT_STRIDE + c2] = f2bf(fmaf(val, P[OFF_DBN_S + ch], P[OFF_DBN_O + ch]));
            } else {
                XT[lane * XT_STRIDE + c2] = (c2 == 264) ? (u16)0x3F80 : (u16)0;
            }
        }
        __syncthreads();
        // MFMA: D[v][c] = XT . W0A^T   (M=64 v, N=64 c, K=288)
        f32x4 acc[4];
#pragma unroll
        for (int i = 0; i < 4; ++i) acc[i] = (f32x4){0.f, 0.f, 0.f, 0.f};
        for (int ks = 0; ks < 9; ++ks) {
            const int k0 = ks * 32 + quad * 8;
            bf16x8 af = *(const bf16x8*)&XT[(m0 + l16) * XT_STRIDE + k0];
#pragma unroll
            for (int ni = 0; ni < 4; ++ni) {
                bf16x8 bf = *(const bf16x8*)&W0Ag[(u32)(ni * 16 + l16) * 288 + k0];
                acc[ni] = __builtin_amdgcn_mfma_f32_16x16x32_bf16(af, bf, acc[ni], 0, 0, 0);
            }
        }
        // write H[c][v]  (row=v=quad*4+r, col=c=ni*16+l16)
        const int vloc = vh * 64 + m0 + quad * 4;
#pragma unroll
        for (int ni = 0; ni < 4; ++ni) {
            const int c = ni * 16 + l16;
            ushort4 rr; u16* rp = (u16*)&rr;
#pragma unroll
            for (int r = 0; r < 4; ++r) rp[r] = f2bf(acc[ni][r]);
            *(ushort4*)&H[c * 136 + vloc] = rr;
        }
    }
    __syncthreads();   // H complete; XT readers done -> amT may overwrite

    // ---- phase B: graph conv ----
    // stage amT[w][v] (packed 2 v's per write)
    const u32 abase = (((u32)n * T_ + t) * V_) * V_;
    for (int e = tid; e < 64 * 128; e += 256) {
        int vvp = e >> 7, w = e & 127;
        int vv = vvp * 2;
        float a0 = ldin(a, abase + (u32)vv * 128u + w, f32)       * ldin(imp0, (u32)vv * 128u + w, f32);
        float a1 = ldin(a, abase + (u32)(vv + 1) * 128u + w, f32) * ldin(imp0, (u32)(vv + 1) * 128u + w, f32);
        u32 pk = (u32)f2bf(a0) | ((u32)f2bf(a1) << 16);
        *(u32*)&amT[w * 136 + vv] = pk;
    }
    __syncthreads();
    // G[c][w] = H[c][v] . AM[v][w]   (M=64 c, N=128 w, K=128 v)
    const int n0w = wid * 32;
    f32x4 acc[4][2];
#pragma unroll
    for (int mi = 0; mi < 4; ++mi) { acc[mi][0] = (f32x4){0,0,0,0}; acc[mi][1] = (f32x4){0,0,0,0}; }
#pragma unroll
    for (int ks = 0; ks < 4; ++ks) {
        const int k0 = ks * 32 + quad * 8;
        bf16x8 bf0 = *(const bf16x8*)&amT[(n0w + l16) * 136 + k0];
        bf16x8 bf1 = *(const bf16x8*)&amT[(n0w + 16 + l16) * 136 + k0];
#pragma unroll
        for (int mi = 0; mi < 4; ++mi) {
            bf16x8 af = *(const bf16x8*)&H[(mi * 16 + l16) * 136 + k0];
            acc[mi][0] = __builtin_amdgcn_mfma_f32_16x16x32_bf16(af, bf0, acc[mi][0], 0, 0, 0);
            acc[mi][1] = __builtin_amdgcn_mfma_f32_16x16x32_bf16(af, bf1, acc[mi][1], 0, 0, 0);
        }
    }
#pragma unroll
    for (int mi = 0; mi < 4; ++mi) {
        const int c0 = mi * 16 + quad * 4;
        const float4 s4 = *(const float4*)&P[OFF_A0S + c0];
        const float4 o4 = *(const float4*)&P[OFF_A0O + c0];
        const float ss[4] = {s4.x, s4.y, s4.z, s4.w};
        const float oo[4] = {o4.x, o4.y, o4.z, o4.w};
#pragma unroll
        for (int ni = 0; ni < 2; ++ni) {
            const int w = n0w + ni * 16 + l16;
            ushort4 rr; u16* rp = (u16*)&rr;
#pragma unroll
            for (int r = 0; r < 4; ++r) {
                float y = fmaf(acc[mi][ni][r], ss[r], oo[r]);
                float alv = ldin(al0, ((u32)(c0 + r) * 32 + t) * 128 + w, f32);
                rp[r] = f2bf((y >= 0.f) ? y : alv * y);
            }
            *(ushort4*)&g0[((u32)(n * 32 + t) * 128 + w) * 64 + c0] = rr;
        }
    }
}

// ---------------- MFMA tconv0 v2: 2 outputs/block, slice-major, reg-prefetch pipeline ----------------
// XCD-swizzled grid (512): each XCD keeps 4 n-slices of g0 L2-resident.
__global__ __launch_bounds__(256) void k_tconv0(const u16* __restrict__ WTAg, const float* __restrict__ P,
                                                const u16* __restrict__ g0, float* __restrict__ L0)
{
    __shared__ __align__(16) u16 Bs[2][128 * 72];
    const int L = blockIdx.x;
    const int xcd = L & 7, slot = L >> 3;
    const int n = xcd + 8 * (slot >> 4);
    const int t0 = (slot & 15) * 2;
    const int tid = threadIdx.x;
    const int lane = tid & 63, wid = tid >> 6;
    const int l16 = lane & 15, quad = lane >> 4;
    const int n0w = wid * 32;

    const int s_lo = (t0 < 4) ? 0 : (t0 - 4);
    const int s_hi = (t0 + 5 > 31) ? 31 : (t0 + 5);

    // direct stage slice s_lo into buf 0
    {
        const u16* src = g0 + (u32)(n * 32 + s_lo) * 8192u;
#pragma unroll
        for (int j = 0; j < 4; ++j) {
            int idx = tid + j * 256;
            *(uint4*)&Bs[0][(idx >> 3) * 72 + (idx & 7) * 8] = *(const uint4*)&src[idx * 8];
        }
    }
    __syncthreads();

    f32x4 acc[2][4][2];
#pragma unroll
    for (int to = 0; to < 2; ++to)
#pragma unroll
        for (int mi = 0; mi < 4; ++mi) { acc[to][mi][0] = (f32x4){0,0,0,0}; acc[to][mi][1] = (f32x4){0,0,0,0}; }

    for (int s = s_lo; s <= s_hi; ++s) {
        const int buf = (s - s_lo) & 1;
        uint4 pf[4];
        if (s < s_hi) {
            const u16* src = g0 + (u32)(n * 32 + (s + 1)) * 8192u;
#pragma unroll
            for (int j = 0; j < 4; ++j) pf[j] = *(const uint4*)&src[(tid + j * 256) * 8];
        }
        const int k0t = s - t0 + 4, k1t = k0t - 1;   // taps for outputs t0, t0+1
#pragma unroll
        for (int ks = 0; ks < 2; ++ks) {
            const int k0 = ks * 32 + quad * 8;
            bf16x8 b0 = *(const bf16x8*)&Bs[buf][(n0w + l16) * 72 + k0];
            bf16x8 b1 = *(const bf16x8*)&Bs[buf][(n0w + 16 + l16) * 72 + k0];
            if (k0t >= 0 && k0t <= 8) {
#pragma unroll
                for (int mi = 0; mi < 4; ++mi) {
                    bf16x8 af = *(const bf16x8*)&WTAg[(u32)k0t * 4096 + (u32)(mi * 16 + l16) * 64 + k0];
                    acc[0][mi][0] = __builtin_amdgcn_mfma_f32_16x16x32_bf16(af, b0, acc[0][mi][0], 0, 0, 0);
                    acc[0][mi][1] = __builtin_amdgcn_mfma_f32_16x16x32_bf16(af, b1, acc[0][mi][1], 0, 0, 0);
                }
            }
            if (k1t >= 0 && k1t <= 8) {
#pragma unroll
                for (int mi = 0; mi < 4; ++mi) {
                    bf16x8 af = *(const bf16x8*)&WTAg[(u32)k1t * 4096 + (u32)(mi * 16 + l16) * 64 + k0];
                    acc[1][mi][0] = __builtin_amdgcn_mfma_f32_16x16x32_bf16(af, b0, acc[1][mi][0], 0, 0, 0);
                    acc[1][mi][1] = __builtin_amdgcn_mfma_f32_16x16x32_bf16(af, b1, acc[1][mi][1], 0, 0, 0);
                }
            }
        }
        if (s < s_hi) {
#pragma unroll
            for (int j = 0; j < 4; ++j) {
                int idx = tid + j * 256;
                *(uint4*)&Bs[buf ^ 1][(idx >> 3) * 72 + (idx & 7) * 8] = pf[j];
            }
        }
        __syncthreads();
    }

#pragma unroll
    for (int to = 0; to < 2; ++to) {
        const int t = t0 + to;
#pragma unroll
        for (int mi = 0; mi < 4; ++mi) {
            const int ob = mi * 16 + quad * 4;
            const float4 s4 = *(const float4*)&P[OFF_B0S + ob];
            const float4 o4 = *(const float4*)&P[OFF_B0O + ob];
            const float ss[4] = {s4.x, s4.y, s4.z, s4.w};
            const float oo[4] = {o4.x, o4.y, o4.z, o4.w};
#pragma unroll
            for (int ni = 0; ni < 2; ++ni) {
                const int v = n0w + ni * 16 + l16;
#pragma unroll
                for (int r = 0; r < 4; ++r)
                    L0[((u32)(n * 64 + ob + r) * 32 + t) * 128 + v] = fmaf(acc[to][mi][ni][r], ss[r], oo[r]);
            }
        }
    }
}

// ---------------- pointwise conv 1 + graph conv 1 (w=0 only) + BN1a + PReLU -> g1p ----------------
__global__ __launch_bounds__(128) void k_pw1(const void* __restrict__ a, const void* __restrict__ imp1,
                                             const void* __restrict__ al1, const float* __restrict__ P,
                                             const float* __restrict__ L0, float* __restrict__ g1p,
                                             const int* __restrict__ flagp)
{
    __shared__ float part[V_ * 65];
    __shared__ float red2[128];
    const int f32 = *flagp;
    const int t = blockIdx.x, n = blockIdx.y;
    const int tid = threadIdx.x;
    const int v = tid;
    float acc[CO_];
#pragma unroll
    for (int o = 0; o < CO_; ++o) acc[o] = P[OFF_BW1 + o];
    const float* W = P + OFF_W1;
    const u32 base = (u32)n * (CO_ * T_ * V_) + (u32)t * V_ + (u32)v;
    for (int c = 0; c < CO_; ++c) {
        float xv = L0[base + (u32)c * (T_ * V_)];
        const float* wr = W + c * CO_;
#pragma unroll
        for (int o = 0; o < CO_; ++o) acc[o] = fmaf(xv, wr[o], acc[o]);
    }
    float amv = ldin(a, (((u32)n * T_ + t) * V_ + v) * V_ + 0u, f32) * ldin(imp1, (u32)v * V_ + 0u, f32);
#pragma unroll
    for (int o = 0; o < CO_; ++o) part[v * 65 + o] = acc[o] * amv;
    __syncthreads();
    const int o = tid & 63, hh = tid >> 6;
    float s = 0.f;
    for (int vv = hh * 64; vv < hh * 64 + 64; ++vv) s += part[vv * 65 + o];
    red2[tid] = s;
    __syncthreads();
    if (tid < 64) {
        float g = red2[tid] + red2[64 + tid];
        float y = fmaf(g, P[OFF_A1S + o], P[OFF_A1O + o]);
        float alv = ldin(al1, ((u32)o * T_ + t) * V_ + 0u, f32);
        y = (y >= 0.f) ? y : alv * y;
        g1p[((u32)n * CO_ + o) * T_ + t] = y;
    }
}

// ---------------- temporal conv 1 (v=0 only) + BN1b(+bt1) + residual + transpose-out ----------------
__global__ __launch_bounds__(64) void k_tconv1(const void* __restrict__ wt1, const float* __restrict__ P,
                                               const float* __restrict__ g1p, const float* __restrict__ L0,
                                               void* __restrict__ out, const int* __restrict__ flagp)
{
    __shared__ float gl[CO_ * KT_];
    const int f32 = *flagp;
    const int t = blockIdx.x, n = blockIdx.y;
    const int tid = threadIdx.x;
    for (int e = tid; e < CO_ * KT_; e += 64) {
        int i = e / KT_, kk = e - i * KT_;
        int tt = t + kk - 4;
        gl[e] = (tt >= 0 && tt < T_) ? g1p[((u32)n * CO_ + i) * T_ + tt] : 0.f;
    }
    __syncthreads();
    float acc = 0.f;
    for (int i = 0; i < CO_; ++i) {
#pragma unroll
        for (int k = 0; k < KT_; ++k) {
            float wv = ldin(wt1, ((u32)(k * CO_ + i)) * CO_ + tid, f32);
            acc = fmaf(gl[i * KT_ + k], wv, acc);
        }
    }
    float y = fmaf(acc, P[OFF_B1S + tid], P[OFF_B1O + tid]);
    y += L0[(u32)n * (CO_ * T_ * V_) + (u32)tid * (T_ * V_) + (u32)t * V_ + 0];
    const u32 oi = ((u32)n * T_ + t) * CO_ + tid;
    if (f32) ((float*)out)[oi] = y;
    else     ((u16*)out)[oi]   = f2bf(y);
}

__global__ void k_fail(u16* out, int nel) {
    int i = blockIdx.x * 256 + threadIdx.x;
    if (i < nel) out[i] = 0x7f80; // +inf marker: ws too small
}

extern "C" void kernel_launch(void* const* d_in, const int* in_sizes, int n_in,
                              void* d_out, int out_size, void* d_ws, size_t ws_size,
                              hipStream_t stream)
{
    const void* xin  = d_in[0];
    const void* bin  = d_in[1];
    const void* cin2 = d_in[2];
    const void* a    = d_in[3];
    const void* dbn_g = d_in[4];
    const void* dbn_b = d_in[5];
    const void* dbn_m = d_in[6];
    const void* dbn_v = d_in[7];
    const void* w0  = d_in[8];
    const void* bw0 = d_in[9];
    const void* imp0 = d_in[10];
    const void* g0a = d_in[11];
    const void* b0a = d_in[12];
    const void* m0a = d_in[13];
    const void* v0a = d_in[14];
    const void* al0 = d_in[15];
    const void* wt0 = d_in[16];
    const void* bt0 = d_in[17];
    const void* g0b = d_in[18];
    const void* b0b = d_in[19];
    const void* m0b = d_in[20];
    const void* v0b = d_in[21];
    const void* w1  = d_in[22];
    const void* bw1 = d_in[23];
    const void* imp1 = d_in[24];
    const void* g1a = d_in[25];
    const void* b1a = d_in[26];
    const void* m1a = d_in[27];
    const void* v1a = d_in[28];
    const void* al1 = d_in[29];
    const void* wt1 = d_in[30];
    const void* bt1 = d_in[31];
    const void* g1b = d_in[32];
    const void* b1b = d_in[33];
    const void* m1b = d_in[34];
    const void* v1b = d_in[35];

    if (ws_size < (size_t)B_END) {
        k_fail<<<(out_size + 255) / 256, 256, 0, stream>>>((u16*)d_out, out_size);
        return;
    }
    char* w = (char*)d_ws;
    float* P    = (float*)(w + B_P);
    int*   flg  = (int*)(w + B_FLAG);
    u16*   W0A  = (u16*)(w + B_W0A);
    u16*   WTA  = (u16*)(w + B_WTA);
    u16*   g0   = (u16*)(w + B_G0);
    float* L0   = (float*)(w + B_L0);
    float* g1p  = (float*)(w + B_G1P);

    k_detect<<<1, 64, 0, stream>>>(a, flg);
    k_prep<<<(PREP_TOTAL + 255) / 256, 256, 0, stream>>>(
        dbn_g, dbn_b, dbn_m, dbn_v, w0, bw0, g0a, b0a, m0a, v0a,
        bt0, g0b, b0b, m0b, v0b, w1, bw1, g1a, b1a, m1a, v1a,
        bt1, g1b, b1b, m1b, v1b, wt0, P, W0A, WTA, flg);

    dim3 grid(T_, N_);
    k_l0    <<<grid, 256, 0, stream>>>(xin, bin, cin2, a, imp0, al0, P, W0A, g0, flg);
    k_tconv0<<<512,  256, 0, stream>>>(WTA, P, g0, L0);
    k_pw1   <<<grid, 128, 0, stream>>>(a, imp1, al1, P, L0, g1p, flg);
    k_tconv1<<<grid,  64, 0, stream>>>(wt1, P, g1p, L0, d_out, flg);
}

// Round 5
// 600.933 us; speedup vs baseline: 1.0805x; 1.0805x over previous
//
#include <hip/hip_runtime.h>
#include <hip/hip_bf16.h>

typedef unsigned short u16;
typedef unsigned int   u32;

#define N_   32
#define T_   32
#define V_   128
#define CO_  64
#define KT_  9
#define EPS_ 1e-3f

// ---- param table (float offsets inside ws). DBI = interleaved (scale,offset) pairs ----
#define OFF_DBI   0          // 2*33792 floats
#define OFF_W0    67584      // 264*64 f32 (legacy, unused)
#define OFF_BW0   84480
#define OFF_A0S   84544
#define OFF_A0O   84608
#define OFF_B0S   84672      // includes bt0 fold
#define OFF_B0O   84736
#define OFF_W1    84800      // 64*64 f32
#define OFF_BW1   88896
#define OFF_A1S   88960
#define OFF_A1O   89024
#define OFF_B1S   89088      // includes bt1 fold
#define OFF_B1O   89152
#define PREP_TOTAL 372608    // + W0A + WTA + al0T

// ---- ws byte layout (unchanged footprint; L0 region reused for r/Sa/col) ----
#define B_P    0
#define B_FLAG 360448
#define B_W0A  360512                    // bf16 64 x 288
#define B_WTA  397440                    // bf16 9 x 64 x 64
#define B_H0   524288                    // al0T: bf16 [t][w][c] 524288 B (in old 16MB slot)
#define B_G0   (B_H0 + 16777216)         // bf16 [n][t][w][i]  16 MB
#define B_L0   (B_G0 + 16777216)         // freed 64MB region:
#define B_R    B_L0                      //   f32 [n][t][64]  262144 B
#define B_SA   (B_L0 + 262144)           //   f32 [n][t]      4096 B
#define B_COL  (B_L0 + 266240)           //   f32 [n][t][64]  262144 B
#define B_G1P  (B_L0 + 33554432)
#define B_END  (B_G1P + 262144)

typedef short bf16x8 __attribute__((ext_vector_type(8)));
typedef float f32x4  __attribute__((ext_vector_type(4)));

__device__ __forceinline__ float bf2f(u16 u) { return __uint_as_float(((u32)u) << 16); }
__device__ __forceinline__ u16 f2bf(float f) {
    u32 x = __float_as_uint(f);
    return (u16)((x + 0x7fffu + ((x >> 16) & 1u)) >> 16);
}
__device__ __forceinline__ float ldin(const void* p, u32 i, int f32) {
    return f32 ? ((const float*)p)[i] : bf2f(((const u16*)p)[i]);
}

// ---------------- dtype detect ----------------
__global__ void k_detect(const void* a, int* flag) {
    if (threadIdx.x == 0 && blockIdx.x == 0) {
        const u16* p = (const u16*)a;
        int cnt = 0;
        for (int i = 0; i < 64; ++i) {
            float v = bf2f(p[2 * i]);
            if (v >= 0.f && v <= 1.0f) ++cnt;
        }
        *flag = (cnt >= 56) ? 0 : 1;
    }
}

// ---------------- param prep ----------------
__global__ void k_prep(const void* dbn_g, const void* dbn_b, const void* dbn_m, const void* dbn_v,
                       const void* w0, const void* bw0,
                       const void* g0a, const void* b0a, const void* m0a, const void* v0a,
                       const void* bt0, const void* g0b, const void* b0b, const void* m0b, const void* v0b,
                       const void* w1, const void* bw1,
                       const void* g1a, const void* b1a, const void* m1a, const void* v1a,
                       const void* bt1, const void* g1b, const void* b1b, const void* m1b, const void* v1b,
                       const void* wt0, const void* al0,
                       float* P, u16* W0A, u16* WTA, u16* al0T, const int* flagp)
{
    const int f32 = *flagp;
    int i = blockIdx.x * 256 + threadIdx.x;
    if (i < 33792) {
        float s = ldin(dbn_g, i, f32) * rsqrtf(ldin(dbn_v, i, f32) + EPS_);
        P[OFF_DBI + 2 * i]     = s;
        P[OFF_DBI + 2 * i + 1] = ldin(dbn_b, i, f32) - ldin(dbn_m, i, f32) * s;
    } else if (i < 50688) { int j = i - 33792; P[OFF_W0 + j] = ldin(w0, j, f32); }
    else if (i < 50752) { int j = i - 50688; P[OFF_BW0 + j] = ldin(bw0, j, f32); }
    else if (i < 50816) { int j = i - 50752;
        float s = ldin(g0a, j, f32) * rsqrtf(ldin(v0a, j, f32) + EPS_);
        P[OFF_A0S + j] = s; P[OFF_A0O + j] = ldin(b0a, j, f32) - ldin(m0a, j, f32) * s;
    } else if (i < 50880) { int j = i - 50816;
        float s = ldin(g0b, j, f32) * rsqrtf(ldin(v0b, j, f32) + EPS_);
        P[OFF_B0S + j] = s; P[OFF_B0O + j] = (ldin(bt0, j, f32) - ldin(m0b, j, f32)) * s + ldin(b0b, j, f32);
    } else if (i < 54976) { int j = i - 50880; P[OFF_W1 + j] = ldin(w1, j, f32); }
    else if (i < 55040) { int j = i - 54976; P[OFF_BW1 + j] = ldin(bw1, j, f32); }
    else if (i < 55104) { int j = i - 55040;
        float s = ldin(g1a, j, f32) * rsqrtf(ldin(v1a, j, f32) + EPS_);
        P[OFF_A1S + j] = s; P[OFF_A1O + j] = ldin(b1a, j, f32) - ldin(m1a, j, f32) * s;
    } else if (i < 55168) { int j = i - 55104;
        float s = ldin(g1b, j, f32) * rsqrtf(ldin(v1b, j, f32) + EPS_);
        P[OFF_B1S + j] = s; P[OFF_B1O + j] = (ldin(bt1, j, f32) - ldin(m1b, j, f32)) * s + ldin(b1b, j, f32);
    } else if (i < 73600) {      // W0A[c][288]: w0^T, row 264 = bw0 bias trick
        int j = i - 55168; int c = j / 288, ci = j - c * 288;
        float val = (ci < 264) ? ldin(w0, (u32)ci * 64 + c, f32)
                  : ((ci == 264) ? ldin(bw0, c, f32) : 0.f);
        W0A[j] = f2bf(val);
    } else if (i < 110464) {     // WTA[k][o][i] = wt0[k][0][i][o]
        int j = i - 73600; int k = j >> 12, rem = j & 4095, o = rem >> 6, ii = rem & 63;
        WTA[j] = f2bf(ldin(wt0, ((u32)(k * 64 + ii)) * 64 + o, f32));
    } else if (i < 372608) {     // al0T[t][w][c] = al0[c][t][w]
        int j = i - 110464; int t = j >> 13, rem = j & 8191, w = rem >> 6, c = rem & 63;
        al0T[j] = f2bf(ldin(al0, ((u32)c * 32 + t) * 128 + w, f32));
    }
}

// ---------------- fused layer-0 v3: u32-pair gather -> pw0 MFMA -> HS -> graph0 MFMA -> g0 ----
// Swizzled LDS: XTS[kb(c2>>3)][v][8] (aligned b128 A-reads), HS[kb(v>>3)][c][8], AMS[w][136].
__global__ __launch_bounds__(256) void k_l0(const void* __restrict__ xin, const void* __restrict__ bin,
                                            const void* __restrict__ cin2, const void* __restrict__ a,
                                            const void* __restrict__ imp0, const u16* __restrict__ al0T,
                                            const float* __restrict__ P, const u16* __restrict__ W0Ag,
                                            u16* __restrict__ g0, const int* __restrict__ flagp)
{
    __shared__ __align__(16) u16 SM16[18432 + 8192];   // 53248 B -> 3 blocks/CU
    u16* XTS = SM16;             // 36 kb * 512
    u16* AMS = SM16;             // [128][136] overlay (17408 <= 18432)
    u16* HS  = SM16 + 18432;     // 16 kb * 512

    const int f32 = *flagp;
    const int t = blockIdx.x, n = blockIdx.y;
    const int tid = threadIdx.x;
    const int lane = tid & 63, wid = tid >> 6;
    const int l16 = lane & 15, quad = lane >> 4;
    const int m0 = wid * 16;

    // ---- phase A: pointwise conv, two v-halves ----
    for (int vh = 0; vh < 2; ++vh) {
        if (vh) __syncthreads();
        for (int it = 0; it < 36; ++it) {
            const int c2 = it * 8 + wid * 2 + (lane >> 5);
            const int l  = lane & 31;
            u16 b0, b1;
            if (c2 < 264) {
                u32 s = (u32)c2 * 4096u + (u32)t * 128u + (u32)(vh * 64 + 2 * l);
                u32 vs = s / 8448u; u32 r2 = s - vs * 8448u;
                u32 ts = r2 / 264u; u32 cc = r2 - ts * 264u;   // cc even -> pair intra-buffer
                u32 base = ((u32)n * 32u + ts) * 128u + vs;
                float e0, e1;
                if (f32) {
                    const float* src; u32 ei;
                    if (cc < 256u)      { src = (const float*)xin;  ei = base * 256u + cc; }
                    else if (cc < 260u) { src = (const float*)bin;  ei = base * 4u + (cc - 256u); }
                    else                { src = (const float*)cin2; ei = base * 4u + (cc - 260u); }
                    float2 p = *(const float2*)(src + ei);
                    e0 = p.x; e1 = p.y;
                } else {
                    const u16* src; u32 ei;
                    if (cc < 256u)      { src = (const u16*)xin;  ei = base * 256u + cc; }
                    else if (cc < 260u) { src = (const u16*)bin;  ei = base * 4u + (cc - 256u); }
                    else                { src = (const u16*)cin2; ei = base * 4u + (cc - 260u); }
                    u32 wv = *(const u32*)(src + ei);
                    e0 = bf2f((u16)wv); e1 = bf2f((u16)(wv >> 16));
                }
                u32 ch = vs * 264u + cc;                        // ch even -> float4 aligned
                float4 dd = *(const float4*)&P[OFF_DBI + 2u * ch];
                b0 = f2bf(fmaf(e0, dd.x, dd.y));
                b1 = f2bf(fmaf(e1, dd.z, dd.w));
            } else {
                b0 = b1 = (c2 == 264) ? (u16)0x3F80 : (u16)0;
            }
            const int kb = c2 >> 3, cr = c2 & 7, v = 2 * (lane & 31);
            XTS[kb * 512 + v * 8 + cr]       = b0;
            XTS[kb * 512 + (v + 1) * 8 + cr] = b1;
        }
        __syncthreads();
        // MFMA: D[v][c] = XT . W0A^T  (M=64 v, N=64 c, K=288)
        f32x4 acc[4];
#pragma unroll
        for (int i = 0; i < 4; ++i) acc[i] = (f32x4){0.f, 0.f, 0.f, 0.f};
        for (int ks = 0; ks < 9; ++ks) {
            const int kb4 = ks * 4 + quad;
            bf16x8 af = *(const bf16x8*)&XTS[kb4 * 512 + (m0 + l16) * 8];
            const int k0 = ks * 32 + quad * 8;
#pragma unroll
            for (int ni = 0; ni < 4; ++ni) {
                bf16x8 bf = *(const bf16x8*)&W0Ag[(u32)(ni * 16 + l16) * 288 + k0];
                acc[ni] = __builtin_amdgcn_mfma_f32_16x16x32_bf16(af, bf, acc[ni], 0, 0, 0);
            }
        }
        const int vloc = vh * 64 + m0 + quad * 4;
#pragma unroll
        for (int ni = 0; ni < 4; ++ni) {
            const int c = ni * 16 + l16;
            ushort4 rr; u16* rp = (u16*)&rr;
#pragma unroll
            for (int r = 0; r < 4; ++r) rp[r] = f2bf(acc[ni][r]);
            *(ushort4*)&HS[(vloc >> 3) * 512 + c * 8 + (vloc & 7)] = rr;
        }
    }
    __syncthreads();   // XTS reads + HS writes complete

    // ---- phase B staging: AMS[w][136] = (a*imp0)^T, u32-pair loads (w,w+1) ----
    const u32 abase = (u32)(n * 32 + t) * 16384u;
    for (int it = 0; it < 32; ++it) {
        const int idx = tid + it * 256;
        const int wp = idx >> 7, vv = idx & 127;
        const int w = 2 * wp;
        float a0, a1, i0, i1;
        if (f32) {
            float2 ap = *(const float2*)((const float*)a + abase + (u32)vv * 128u + w);
            float2 ip = *(const float2*)((const float*)imp0 + (u32)vv * 128u + w);
            a0 = ap.x; a1 = ap.y; i0 = ip.x; i1 = ip.y;
        } else {
            u32 av = *(const u32*)((const u16*)a + abase + (u32)vv * 128u + w);
            u32 iv = *(const u32*)((const u16*)imp0 + (u32)vv * 128u + w);
            a0 = bf2f((u16)av); a1 = bf2f((u16)(av >> 16));
            i0 = bf2f((u16)iv); i1 = bf2f((u16)(iv >> 16));
        }
        AMS[w * 136 + vv]       = f2bf(a0 * i0);
        AMS[(w + 1) * 136 + vv] = f2bf(a1 * i1);
    }
    __syncthreads();

    // ---- phase B MFMA: G[c][w] = H[c][v] . AM[v][w] ----
    const int n0w = wid * 32;
    f32x4 acc[4][2];
#pragma unroll
    for (int mi = 0; mi < 4; ++mi) { acc[mi][0] = (f32x4){0,0,0,0}; acc[mi][1] = (f32x4){0,0,0,0}; }
#pragma unroll
    for (int ks = 0; ks < 4; ++ks) {
        const int k0 = ks * 32 + quad * 8;
        const int kb4 = ks * 4 + quad;
        bf16x8 bf0 = *(const bf16x8*)&AMS[(n0w + l16) * 136 + k0];
        bf16x8 bf1 = *(const bf16x8*)&AMS[(n0w + 16 + l16) * 136 + k0];
#pragma unroll
        for (int mi = 0; mi < 4; ++mi) {
            bf16x8 af = *(const bf16x8*)&HS[kb4 * 512 + (mi * 16 + l16) * 8];
            acc[mi][0] = __builtin_amdgcn_mfma_f32_16x16x32_bf16(af, bf0, acc[mi][0], 0, 0, 0);
            acc[mi][1] = __builtin_amdgcn_mfma_f32_16x16x32_bf16(af, bf1, acc[mi][1], 0, 0, 0);
        }
    }
#pragma unroll
    for (int mi = 0; mi < 4; ++mi) {
        const int c0 = mi * 16 + quad * 4;
        const float4 s4 = *(const float4*)&P[OFF_A0S + c0];
        const float4 o4 = *(const float4*)&P[OFF_A0O + c0];
        const float ss[4] = {s4.x, s4.y, s4.z, s4.w};
        const float oo[4] = {o4.x, o4.y, o4.z, o4.w};
#pragma unroll
        for (int ni = 0; ni < 2; ++ni) {
            const int w = n0w + ni * 16 + l16;
            ushort4 al4 = *(const ushort4*)&al0T[((u32)t * 128 + w) * 64 + c0];
            const u16* ap = (const u16*)&al4;
            ushort4 rr; u16* rp = (u16*)&rr;
#pragma unroll
            for (int r = 0; r < 4; ++r) {
                float y = fmaf(acc[mi][ni][r], ss[r], oo[r]);
                float alv = bf2f(ap[r]);
                rp[r] = f2bf((y >= 0.f) ? y : alv * y);
            }
            *(ushort4*)&g0[((u32)(n * 32 + t) * 128 + w) * 64 + c0] = rr;
        }
    }
}

// ---------------- tconv0 v3: MFMA K-loop + fused r/Sa/L0col epilogue (no full L0!) ----------------
__global__ __launch_bounds__(256) void k_tconv0(const u16* __restrict__ WTAg, const float* __restrict__ P,
                                                const u16* __restrict__ g0,
                                                const void* __restrict__ a, const void* __restrict__ imp1,
                                                float* __restrict__ rbuf, float* __restrict__ SaB,
                                                float* __restrict__ colB, const int* __restrict__ flagp)
{
    __shared__ __align__(16) u16 Bs[2][128 * 72];
    __shared__ float amv2[2][128];
    __shared__ float partS[4][2][64];
    __shared__ float SaS[2];
    const int f32 = *flagp;
    const int L = blockIdx.x;
    const int xcd = L & 7, slot = L >> 3;
    const int n = xcd + 8 * (slot >> 4);
    const int t0 = (slot & 15) * 2;
    const int tid = threadIdx.x;
    const int lane = tid & 63, wid = tid >> 6;
    const int l16 = lane & 15, quad = lane >> 4;
    const int n0w = wid * 32;

    {   // amv for both output t's: a[n][t][v][0] * imp1[v][0]
        const int to = tid >> 7, v = tid & 127;
        float av = ldin(a, (((u32)(n * 32 + t0 + to) * 128u + v) * 128u), f32);
        float iv = ldin(imp1, (u32)v * 128u, f32);
        amv2[to][v] = av * iv;
    }

    const int s_lo = (t0 < 4) ? 0 : (t0 - 4);
    const int s_hi = (t0 + 5 > 31) ? 31 : (t0 + 5);
    {
        const u16* src = g0 + (u32)(n * 32 + s_lo) * 8192u;
#pragma unroll
        for (int j = 0; j < 4; ++j) {
            int idx = tid + j * 256;
            *(uint4*)&Bs[0][(idx >> 3) * 72 + (idx & 7) * 8] = *(const uint4*)&src[idx * 8];
        }
    }
    __syncthreads();

    f32x4 acc[2][4][2];
#pragma unroll
    for (int to = 0; to < 2; ++to)
#pragma unroll
        for (int mi = 0; mi < 4; ++mi) { acc[to][mi][0] = (f32x4){0,0,0,0}; acc[to][mi][1] = (f32x4){0,0,0,0}; }

    for (int s = s_lo; s <= s_hi; ++s) {
        const int buf = (s - s_lo) & 1;
        uint4 pf[4];
        if (s < s_hi) {
            const u16* src = g0 + (u32)(n * 32 + (s + 1)) * 8192u;
#pragma unroll
            for (int j = 0; j < 4; ++j) pf[j] = *(const uint4*)&src[(tid + j * 256) * 8];
        }
        const int k0t = s - t0 + 4, k1t = k0t - 1;
#pragma unroll
        for (int ks = 0; ks < 2; ++ks) {
            const int k0 = ks * 32 + quad * 8;
            bf16x8 b0 = *(const bf16x8*)&Bs[buf][(n0w + l16) * 72 + k0];
            bf16x8 b1 = *(const bf16x8*)&Bs[buf][(n0w + 16 + l16) * 72 + k0];
            if (k0t >= 0 && k0t <= 8) {
#pragma unroll
                for (int mi = 0; mi < 4; ++mi) {
                    bf16x8 af = *(const bf16x8*)&WTAg[(u32)k0t * 4096 + (u32)(mi * 16 + l16) * 64 + k0];
                    acc[0][mi][0] = __builtin_amdgcn_mfma_f32_16x16x32_bf16(af, b0, acc[0][mi][0], 0, 0, 0);
                    acc[0][mi][1] = __builtin_amdgcn_mfma_f32_16x16x32_bf16(af, b1, acc[0][mi][1], 0, 0, 0);
                }
            }
            if (k1t >= 0 && k1t <= 8) {
#pragma unroll
                for (int mi = 0; mi < 4; ++mi) {
                    bf16x8 af = *(const bf16x8*)&WTAg[(u32)k1t * 4096 + (u32)(mi * 16 + l16) * 64 + k0];
                    acc[1][mi][0] = __builtin_amdgcn_mfma_f32_16x16x32_bf16(af, b0, acc[1][mi][0], 0, 0, 0);
                    acc[1][mi][1] = __builtin_amdgcn_mfma_f32_16x16x32_bf16(af, b1, acc[1][mi][1], 0, 0, 0);
                }
            }
        }
        if (s < s_hi) {
#pragma unroll
            for (int j = 0; j < 4; ++j) {
                int idx = tid + j * 256;
                *(uint4*)&Bs[buf ^ 1][(idx >> 3) * 72 + (idx & 7) * 8] = pf[j];
            }
        }
        __syncthreads();
    }

    // ---- epilogue: L0col (v=0), r = Sum_v BN(acc)*amv, Sa = Sum_v amv ----
    if (wid == 0 && l16 == 0) {          // lanes 0,16,32,48: v = 0
#pragma unroll
        for (int to = 0; to < 2; ++to)
#pragma unroll
            for (int mi = 0; mi < 4; ++mi)
#pragma unroll
                for (int r = 0; r < 4; ++r) {
                    const int o = mi * 16 + quad * 4 + r;
                    colB[(u32)(n * 32 + t0 + to) * 64 + o] =
                        fmaf(acc[to][mi][0][r], P[OFF_B0S + o], P[OFF_B0O + o]);
                }
    }
#pragma unroll
    for (int to = 0; to < 2; ++to) {
        const float am0 = amv2[to][n0w + l16];
        const float am1 = amv2[to][n0w + 16 + l16];
#pragma unroll
        for (int mi = 0; mi < 4; ++mi)
#pragma unroll
            for (int r = 0; r < 4; ++r) {
                float val = acc[to][mi][0][r] * am0 + acc[to][mi][1][r] * am1;
                val += __shfl_xor(val, 1);
                val += __shfl_xor(val, 2);
                val += __shfl_xor(val, 4);
                val += __shfl_xor(val, 8);
                if (l16 == 0) partS[wid][to][mi * 16 + quad * 4 + r] = val;
            }
    }
    if (wid < 2) {
        float v = amv2[wid][lane] + amv2[wid][64 + lane];
        v += __shfl_xor(v, 1);  v += __shfl_xor(v, 2);  v += __shfl_xor(v, 4);
        v += __shfl_xor(v, 8);  v += __shfl_xor(v, 16); v += __shfl_xor(v, 32);
        if (lane == 0) SaS[wid] = v;
    }
    __syncthreads();
    if (tid < 128) {
        const int to = tid >> 6, o = tid & 63;
        float racc = partS[0][to][o] + partS[1][to][o] + partS[2][to][o] + partS[3][to][o];
        rbuf[(u32)(n * 32 + t0 + to) * 64 + o] = P[OFF_B0S + o] * racc + P[OFF_B0O + o] * SaS[to];
    }
    if (tid < 2) SaB[(u32)(n * 32) + t0 + tid] = SaS[tid];
}

// ---------------- k_final: pw1-via-r + BN1a + PReLU + tconv1 + BN1b + residual + out ----------------
// grid = N_ blocks, 256 threads; per-n fully self-contained.
__global__ __launch_bounds__(256) void k_final(const void* __restrict__ wt1, const void* __restrict__ al1,
                                               const float* __restrict__ P,
                                               const float* __restrict__ rbuf, const float* __restrict__ SaB,
                                               const float* __restrict__ colB,
                                               void* __restrict__ out, const int* __restrict__ flagp)
{
    __shared__ float rS[64 * 33];
    __shared__ float w1S[64 * 64];
    __shared__ float g1S[64 * 40];
    __shared__ u16  wtS[9 * 64 * 64];
    __shared__ float SaS2[32];
    const int f32 = *flagp;
    const int n = blockIdx.x;
    const int tid = threadIdx.x;
    for (int e = tid; e < 64 * 40; e += 256) g1S[e] = 0.f;
    for (int e = tid; e < 2048; e += 256) {
        int tt = e >> 6, c = e & 63;
        rS[c * 33 + tt] = rbuf[(u32)(n * 32 + tt) * 64 + c];
    }
    for (int e = tid; e < 4096; e += 256) w1S[e] = P[OFF_W1 + e];
    for (int e = tid; e < 36864; e += 256)
        wtS[e] = f32 ? f2bf(((const float*)wt1)[e]) : ((const u16*)wt1)[e];
    if (tid < 32) SaS2[tid] = SaB[n * 32 + tid];
    __syncthreads();

    const int o = tid & 63, tg = tid >> 6;
    const float bw1o = P[OFF_BW1 + o];
    float g1v[8];
#pragma unroll
    for (int j = 0; j < 8; ++j) g1v[j] = bw1o * SaS2[tg * 8 + j];
    for (int c = 0; c < 64; ++c) {
        float wv = w1S[c * 64 + o];
#pragma unroll
        for (int j = 0; j < 8; ++j) g1v[j] = fmaf(wv, rS[c * 33 + tg * 8 + j], g1v[j]);
    }
    const float a1s = P[OFF_A1S + o], a1o = P[OFF_A1O + o];
#pragma unroll
    for (int j = 0; j < 8; ++j) {
        const int tt = tg * 8 + j;
        float y = fmaf(g1v[j], a1s, a1o);
        float alv = ldin(al1, ((u32)o * 32 + tt) * 128, f32);
        y = (y >= 0.f) ? y : alv * y;
        g1S[o * 40 + tt + 4] = y;
    }
    __syncthreads();

    float accv[8];
#pragma unroll
    for (int j = 0; j < 8; ++j) accv[j] = 0.f;
    for (int i = 0; i < 64; ++i) {
        float gr[16];
#pragma unroll
        for (int q = 0; q < 16; ++q) gr[q] = g1S[i * 40 + tg * 8 + q];
#pragma unroll
        for (int k = 0; k < KT_; ++k) {
            float wv = bf2f(wtS[(u32)(k * 64 + i) * 64 + o]);
#pragma unroll
            for (int j = 0; j < 8; ++j) accv[j] = fmaf(wv, gr[j + k], accv[j]);
        }
    }
    const float b1s = P[OFF_B1S + o], b1o = P[OFF_B1O + o];
#pragma unroll
    for (int j = 0; j < 8; ++j) {
        const int tt = tg * 8 + j;
        const u32 oi = (u32)(n * 32 + tt) * 64 + o;
        float y = fmaf(accv[j], b1s, b1o) + colB[oi];
        if (f32) ((float*)out)[oi] = y;
        else     ((u16*)out)[oi]   = f2bf(y);
    }
}

__global__ void k_fail(u16* out, int nel) {
    int i = blockIdx.x * 256 + threadIdx.x;
    if (i < nel) out[i] = 0x7f80; // +inf marker: ws too small
}

extern "C" void kernel_launch(void* const* d_in, const int* in_sizes, int n_in,
                              void* d_out, int out_size, void* d_ws, size_t ws_size,
                              hipStream_t stream)
{
    const void* xin  = d_in[0];
    const void* bin  = d_in[1];
    const void* cin2 = d_in[2];
    const void* a    = d_in[3];
    const void* dbn_g = d_in[4];
    const void* dbn_b = d_in[5];
    const void* dbn_m = d_in[6];
    const void* dbn_v = d_in[7];
    const void* w0  = d_in[8];
    const void* bw0 = d_in[9];
    const void* imp0 = d_in[10];
    const void* g0a = d_in[11];
    const void* b0a = d_in[12];
    const void* m0a = d_in[13];
    const void* v0a = d_in[14];
    const void* al0 = d_in[15];
    const void* wt0 = d_in[16];
    const void* bt0 = d_in[17];
    const void* g0b = d_in[18];
    const void* b0b = d_in[19];
    const void* m0b = d_in[20];
    const void* v0b = d_in[21];
    const void* w1  = d_in[22];
    const void* bw1 = d_in[23];
    const void* imp1 = d_in[24];
    const void* g1a = d_in[25];
    const void* b1a = d_in[26];
    const void* m1a = d_in[27];
    const void* v1a = d_in[28];
    const void* al1 = d_in[29];
    const void* wt1 = d_in[30];
    const void* bt1 = d_in[31];
    const void* g1b = d_in[32];
    const void* b1b = d_in[33];
    const void* m1b = d_in[34];
    const void* v1b = d_in[35];

    if (ws_size < (size_t)B_END) {
        k_fail<<<(out_size + 255) / 256, 256, 0, stream>>>((u16*)d_out, out_size);
        return;
    }
    char* w = (char*)d_ws;
    float* P    = (float*)(w + B_P);
    int*   flg  = (int*)(w + B_FLAG);
    u16*   W0A  = (u16*)(w + B_W0A);
    u16*   WTA  = (u16*)(w + B_WTA);
    u16*   al0T = (u16*)(w + B_H0);
    u16*   g0   = (u16*)(w + B_G0);
    float* rbuf = (float*)(w + B_R);
    float* SaB  = (float*)(w + B_SA);
    float* colB = (float*)(w + B_COL);

    k_detect<<<1, 64, 0, stream>>>(a, flg);
    k_prep<<<(PREP_TOTAL + 255) / 256, 256, 0, stream>>>(
        dbn_g, dbn_b, dbn_m, dbn_v, w0, bw0, g0a, b0a, m0a, v0a,
        bt0, g0b, b0b, m0b, v0b, w1, bw1, g1a, b1a, m1a, v1a,
        bt1, g1b, b1b, m1b, v1b, wt0, al0, P, W0A, WTA, al0T, flg);

    dim3 grid(T_, N_);
    k_l0    <<<grid, 256, 0, stream>>>(xin, bin, cin2, a, imp0, al0T, P, W0A, g0, flg);
    k_tconv0<<<512,  256, 0, stream>>>(WTA, P, g0, a, imp1, rbuf, SaB, colB, flg);
    k_final <<<N_,   256, 0, stream>>>(wt1, al1, P, rbuf, SaB, colB, d_out, flg);
}